// Round 1
// baseline (234.089 us; speedup 1.0000x reference)
//
#include <hip/hip_runtime.h>
#include <hip/hip_bf16.h>

#define B_SZ   128
#define T_SZ   2048
#define ENCH   512
#define ATTN_  128
#define S_SPLIT 8
#define ROWS   64
#define CHUNK  (T_SZ / S_SPLIT)   // 256 rows per block

typedef __attribute__((ext_vector_type(8))) short short8;
typedef __attribute__((ext_vector_type(4))) float f32x4;
typedef __attribute__((ext_vector_type(4))) unsigned short ushort4v;

__device__ __forceinline__ unsigned short f2bf_rne(float f) {
  unsigned u = __builtin_bit_cast(unsigned, f);
  u += 0x7FFFu + ((u >> 16) & 1u);          // round-to-nearest-even
  return (unsigned short)(u >> 16);
}
__device__ __forceinline__ float bf2f(unsigned short s) {
  return __builtin_bit_cast(float, ((unsigned)s) << 16);
}

// ---- K0b: W_enc fp32 -> bf16 (row-major [128][512]) ----
__global__ void k_convert_wenc(const float* __restrict__ w,
                               unsigned short* __restrict__ o) {
  int i = blockIdx.x * 256 + threadIdx.x;   // 16384 threads x 4 elems
  float4 v = reinterpret_cast<const float4*>(w)[i];
  ushort4v u = { f2bf_rne(v.x), f2bf_rne(v.y), f2bf_rne(v.z), f2bf_rne(v.w) };
  reinterpret_cast<ushort4v*>(o)[i] = u;
}

// ---- K0a: dec_proj[b][a] = sum_h dec[b,h] * W_dec[a,h]  (fp32) ----
__global__ void k_decproj(const float* __restrict__ dec,
                          const float* __restrict__ wdec,
                          float* __restrict__ out) {
  __shared__ float dh[ENCH];
  int b = blockIdx.x, tid = threadIdx.x;    // 128 threads
  for (int i = tid; i < ENCH; i += 128) dh[i] = dec[b * ENCH + i];
  __syncthreads();
  const float4* wr4 = reinterpret_cast<const float4*>(wdec + tid * ENCH);
  float acc = 0.f;
  for (int h4 = 0; h4 < ENCH / 4; ++h4) {
    float4 w4 = wr4[h4];
    acc += dh[h4 * 4 + 0] * w4.x + dh[h4 * 4 + 1] * w4.y +
           dh[h4 * 4 + 2] * w4.z + dh[h4 * 4 + 3] * w4.w;
  }
  out[b * ATTN_ + tid] = acc;
}

// ---- K1: fused enc_proj + tanh + scores + online-softmax context partials ----
__global__ __launch_bounds__(512, 4) void k_main(
    const float* __restrict__ enc,            // [B,T,512] fp32
    const unsigned short* __restrict__ wenc,  // [128,512] bf16
    const float* __restrict__ decproj,        // [B,128] fp32
    const float* __restrict__ vw,             // [128] fp32
    float* __restrict__ scores_raw,           // d_out+B*512: [B,T] raw scores
    float* __restrict__ ctx_part,             // [B,S,512]
    float* __restrict__ ml_part)              // [B,S,2]
{
  const int s    = blockIdx.x;
  const int b    = blockIdx.y;
  const int tid  = threadIdx.x;
  const int lane = tid & 63;
  const int wave = tid >> 6;      // 8 waves, wave owns attn cols [wave*16, wave*16+16)
  const int l15  = lane & 15;
  const int g    = lane >> 4;

  __shared__ unsigned short enc_lds[ROWS * ENCH]; // 64 KiB, XOR-swizzled rows
  __shared__ float scores_buf[ROWS];

  // Persistent B fragments: B[k][col] = W_enc[col][k]; lane holds col=l15, k=g*8..g*8+7
  const int acol = wave * 16 + l15;
  short8 bfrag[16];
  {
    const unsigned short* wp = wenc + acol * ENCH;
#pragma unroll
    for (int ks = 0; ks < 16; ++ks)
      bfrag[ks] = *reinterpret_cast<const short8*>(wp + ks * 32 + g * 8);
  }
  const float vlane = vw[acol];
  const float dlane = decproj[b * ATTN_ + acol];

  float m_run = -INFINITY, l_run = 0.f, ctx = 0.f;   // thread owns h = tid

  const int t0 = s * CHUNK;
  const float* encb = enc + ((size_t)b * T_SZ + t0) * ENCH;

  for (int st = 0; st < CHUNK / ROWS; ++st) {
    __syncthreads();  // previous subtile's ctx reads done before overwrite

    // ---- stage 64x512 fp32 -> bf16 LDS, swizzle byte ^= ((row&7)<<4) ----
    const float* src = encb + st * ROWS * ENCH;
#pragma unroll 4
    for (int r = 0; r < 16; ++r) {
      int i4 = r * 512 + tid;                 // float4 index, 8192 per subtile
      float4 v = reinterpret_cast<const float4*>(src)[i4];
      int fo   = i4 * 4;
      int row  = fo >> 9;
      int colb = (fo & 511) * 2;
      ushort4v u = { f2bf_rne(v.x), f2bf_rne(v.y), f2bf_rne(v.z), f2bf_rne(v.w) };
      *reinterpret_cast<ushort4v*>(
          (char*)enc_lds + row * 1024 + (colb ^ ((row & 7) << 4))) = u;
    }
    if (tid < ROWS) scores_buf[tid] = 0.f;
    __syncthreads();

    // ---- MFMA: proj[row][acol] over K=512 ----
    f32x4 acc[4];
#pragma unroll
    for (int mt = 0; mt < 4; ++mt) acc[mt] = (f32x4){0.f, 0.f, 0.f, 0.f};
#pragma unroll
    for (int ks = 0; ks < 16; ++ks) {
      int kbyte = (ks * 32 + g * 8) * 2;
#pragma unroll
      for (int mt = 0; mt < 4; ++mt) {
        int row = mt * 16 + l15;
        short8 a = *reinterpret_cast<const short8*>(
            (const char*)enc_lds + row * 1024 + (kbyte ^ ((row & 7) << 4)));
        acc[mt] = __builtin_amdgcn_mfma_f32_16x16x32_bf16(a, bfrag[ks], acc[mt], 0, 0, 0);
      }
    }

    // ---- energy = tanh(proj + dec_proj); partial score = sum over 16 cols ----
    // C/D layout: col = l15, row = mt*16 + 4*g + reg
#pragma unroll
    for (int mt = 0; mt < 4; ++mt) {
#pragma unroll
      for (int r = 0; r < 4; ++r) {
        float e = tanhf(acc[mt][r] + dlane) * vlane;
        e += __shfl_xor(e, 1);
        e += __shfl_xor(e, 2);
        e += __shfl_xor(e, 4);
        e += __shfl_xor(e, 8);
        if (l15 == 0) atomicAdd(&scores_buf[mt * 16 + g * 4 + r], e);
      }
    }
    __syncthreads();

    if (tid < ROWS)
      scores_raw[(size_t)b * T_SZ + t0 + st * ROWS + tid] = scores_buf[tid];

    // ---- online softmax update + context accumulation (lane owns h = tid) ----
    float smax = -INFINITY;
#pragma unroll 8
    for (int t = 0; t < ROWS; ++t) smax = fmaxf(smax, scores_buf[t]);
    float m_new = fmaxf(m_run, smax);
    float scale = __expf(m_run - m_new);   // exp(-inf)=0 on first subtile
    l_run *= scale;
    ctx   *= scale;
#pragma unroll 4
    for (int t = 0; t < ROWS; ++t) {
      float p = __expf(scores_buf[t] - m_new);
      l_run += p;
      unsigned short ev = *reinterpret_cast<const unsigned short*>(
          (const char*)enc_lds + t * 1024 + ((tid * 2) ^ ((t & 7) << 4)));
      ctx += p * bf2f(ev);
    }
    m_run = m_new;
  }

  ctx_part[((size_t)b * S_SPLIT + s) * ENCH + tid] = ctx;
  if (tid == 0) {
    ml_part[((size_t)b * S_SPLIT + s) * 2 + 0] = m_run;
    ml_part[((size_t)b * S_SPLIT + s) * 2 + 1] = l_run;
  }
}

// ---- K2: merge splits, write context, normalize weights in place ----
__global__ void k_combine(const float* __restrict__ ctx_part,
                          const float* __restrict__ ml_part,
                          float* __restrict__ out_ctx,   // [B,512]
                          float* __restrict__ weights)   // [B,T], holds raw scores
{
  __shared__ float fac[S_SPLIT];
  __shared__ float Msh, Lsh;
  int b = blockIdx.x, tid = threadIdx.x;   // 256 threads
  if (tid == 0) {
    float M = -INFINITY;
    for (int s2 = 0; s2 < S_SPLIT; ++s2)
      M = fmaxf(M, ml_part[(b * S_SPLIT + s2) * 2]);
    float L = 0.f;
    for (int s2 = 0; s2 < S_SPLIT; ++s2) {
      float f = __expf(ml_part[(b * S_SPLIT + s2) * 2] - M);
      fac[s2] = f;
      L += f * ml_part[(b * S_SPLIT + s2) * 2 + 1];
    }
    Msh = M; Lsh = L;
  }
  __syncthreads();
  float M = Msh, Linv = 1.f / Lsh;
  for (int h = tid; h < ENCH; h += 256) {
    float a = 0.f;
    for (int s2 = 0; s2 < S_SPLIT; ++s2)
      a += ctx_part[(b * S_SPLIT + s2) * ENCH + h] * fac[s2];
    out_ctx[b * ENCH + h] = a * Linv;
  }
  for (int t = tid; t < T_SZ; t += 256) {
    float raw = weights[(size_t)b * T_SZ + t];
    weights[(size_t)b * T_SZ + t] = __expf(raw - M) * Linv;
  }
}

extern "C" void kernel_launch(void* const* d_in, const int* in_sizes, int n_in,
                              void* d_out, int out_size, void* d_ws, size_t ws_size,
                              hipStream_t stream) {
  const float* enc  = (const float*)d_in[0];
  const float* dec  = (const float*)d_in[1];
  const float* wenc = (const float*)d_in[2];
  const float* wdec = (const float*)d_in[3];
  const float* vw   = (const float*)d_in[4];

  float* out     = (float*)d_out;
  float* out_ctx = out;                       // [B,512]
  float* out_w   = out + B_SZ * ENCH;         // [B,T] (raw scores, then weights)

  char* ws = (char*)d_ws;
  unsigned short* wenc_bf = (unsigned short*)ws;                    // 131072 B
  float* decproj  = (float*)(ws + 131072);                          // 65536 B
  float* ml_part  = (float*)(ws + 131072 + 65536);                  // 8192 B
  float* ctx_part = (float*)(ws + 131072 + 65536 + 8192);           // 2 MiB

  hipLaunchKernelGGL(k_convert_wenc, dim3(64), dim3(256), 0, stream, wenc, wenc_bf);
  hipLaunchKernelGGL(k_decproj, dim3(B_SZ), dim3(128), 0, stream, dec, wdec, decproj);
  hipLaunchKernelGGL(k_main, dim3(S_SPLIT, B_SZ), dim3(512), 0, stream,
                     enc, wenc_bf, decproj, vw, out_w, ctx_part, ml_part);
  hipLaunchKernelGGL(k_combine, dim3(B_SZ), dim3(256), 0, stream,
                     ctx_part, ml_part, out_ctx, out_w);
}